// Round 5
// baseline (883.571 us; speedup 1.0000x reference)
//
#include <hip/hip_runtime.h>
#include <hip/hip_bf16.h>

typedef unsigned short ushort_t;
typedef __bf16 bf16x8 __attribute__((ext_vector_type(8)));
typedef float f32x4 __attribute__((ext_vector_type(4)));
typedef short s16x8 __attribute__((ext_vector_type(8)));

__device__ __forceinline__ float b2f(ushort_t u) {
    union { unsigned u; float f; } x;
    x.u = ((unsigned)u) << 16;
    return x.f;
}
__device__ __forceinline__ ushort_t f2b(float f) {
    union { float f; unsigned u; } x;
    x.f = f;
    unsigned r = x.u + 0x7fffu + ((x.u >> 16) & 1u);
    return (ushort_t)(r >> 16);
}

// async global->LDS, 16B per lane. LDS dest must be wave-uniform base
// (HW adds lane*16); global src is per-lane.
__device__ __forceinline__ void glds16(const ushort_t* g, ushort_t* l) {
    __builtin_amdgcn_global_load_lds(
        (const __attribute__((address_space(1))) void*)g,
        (__attribute__((address_space(3))) void*)l, 16, 0, 0);
}

// ---------- transpose fp32 -> bf16: dst[C][R] = bf16(src[R][C]^T) ----------
__global__ void transpose_k(const float* __restrict__ src, ushort_t* __restrict__ dst,
                            int R, int C) {
    long i = (long)blockIdx.x * 256 + threadIdx.x;
    if (i < (long)R * C) {
        int c = (int)(i / R);
        int r = (int)(i % R);
        dst[i] = f2b(src[(long)r * C + c]);
    }
}

// ---------- concat 3 fp32 bias vectors ----------
__global__ void concat3_k(const float* a, const float* b, const float* c,
                          float* dst, int n) {
    int i = blockIdx.x * 256 + threadIdx.x;
    if (i < 3 * n) dst[i] = (i < n) ? a[i] : (i < 2 * n ? b[i - n] : c[i - 2 * n]);
}

// ---------- LayerNorm over 512 fp32 elems per row -> bf16 out ----------
__global__ __launch_bounds__(256) void ln_kernel(
    const float* __restrict__ x, long xstride,
    const float* __restrict__ g, const float* __restrict__ be,
    ushort_t* __restrict__ out, long ostride) {
    int r = blockIdx.x, t = threadIdx.x;
    const float* row = x + (long)r * xstride;
    float2 p = *(const float2*)(row + 2 * t);
    float v0 = p.x, v1 = p.y;
    float s = v0 + v1, ss = v0 * v0 + v1 * v1;
#pragma unroll
    for (int off = 32; off; off >>= 1) {
        s += __shfl_xor(s, off, 64);
        ss += __shfl_xor(ss, off, 64);
    }
    __shared__ float sb[8];
    int w = t >> 6;
    if ((t & 63) == 0) { sb[w] = s; sb[4 + w] = ss; }
    __syncthreads();
    s = sb[0] + sb[1] + sb[2] + sb[3];
    ss = sb[4] + sb[5] + sb[6] + sb[7];
    float mean = s * (1.f / 512.f);
    float var = ss * (1.f / 512.f) - mean * mean;
    float rstd = rsqrtf(var + 1e-5f);
    float2 gp = *(const float2*)(g + 2 * t);
    float2 bp = *(const float2*)(be + 2 * t);
    ushort2 q;
    q.x = f2b((v0 - mean) * rstd * gp.x + bp.x);
    q.y = f2b((v1 - mean) * rstd * gp.y + bp.y);
    *(ushort2*)(out + (long)r * ostride + 2 * t) = q;
}

// ---------- MFMA GEMM: C[M,N] = A[M,K](bf16) * Bt[N,K](bf16)^T + bias(f32)
//            (+ res(f32)) (+relu); out bf16 or fp32 ----------
// r4 theory: limiter is LATENCY-HIDING CONCURRENCY, not bytes/schedule.
// 128x128 tile, BK=32, 256 thr (4 waves 2x2), dbuf LDS = 32KB -> 5 blocks/CU
// schedulable; grids are 4-12 blocks/CU so each CU keeps ~4-5 blocks whose
// vmcnt-drain barriers mutually overlap (m114 mechanism that made m97 fast).
// 1-D grid + bijective XCD remap: each XCD owns a contiguous m-range, walks
// n fastest -> same-XCD co-resident blocks reuse ONE A-panel per L2.
__global__ __launch_bounds__(256, 5) void gemm_kernel(
    const ushort_t* __restrict__ A, const ushort_t* __restrict__ Bt,
    const float* __restrict__ bias,
    const float* __restrict__ res, long res_stride,
    void* __restrict__ outp, long out_stride, int out_is_f32,
    int K, int relu, int nTiles) {
    __shared__ __align__(16) ushort_t lA[2][128 * 32];
    __shared__ __align__(16) ushort_t lB[2][128 * 32];
    const int t = threadIdx.x;
    // XCD-aware remap (nwg % 8 == 0 for all launches; bijective):
    // xcd = bid%8 owns m-tiles [xcd*mPerXcd, (xcd+1)*mPerXcd), n fastest.
    const int bid = blockIdx.x;
    const int xcd = bid & 7;
    const int jj = bid >> 3;
    const int mPerXcd = (int)gridDim.x / (nTiles * 8);
    const int mt = xcd * mPerXcd + jj / nTiles;
    const int nt = jj % nTiles;
    const int m0 = mt * 128, n0 = nt * 128;

    const int wave = t >> 6, lane = t & 63, quad = lane >> 4, l16 = lane & 15;
    const int wm = (wave & 1) * 64, wn = (wave >> 1) * 64;
    f32x4 acc[4][4];
#pragma unroll
    for (int i = 0; i < 4; i++)
#pragma unroll
        for (int j = 0; j < 4; j++) acc[i][j] = (f32x4){0.f, 0.f, 0.f, 0.f};

    // staging map: thread t covers tile elems [t*8, t*8+8) of each 4KB round
    const int srow = t >> 2;          // 0..63
    const int scol = (t & 3) * 8;     // 0,8,16,24
    const ushort_t* gA0 = A + (long)(m0 + srow) * K + scol;
    const ushort_t* gA1 = gA0 + (long)64 * K;
    const ushort_t* gB0 = Bt + (long)(n0 + srow) * K + scol;
    const ushort_t* gB1 = gB0 + (long)64 * K;
    const int lofs = wave * 512;      // wave-uniform base (HW adds lane*16B)

#define ISSUE_TILE(sl, k0)                             \
    do {                                               \
        glds16(gA0 + (k0), &lA[sl][lofs]);             \
        glds16(gA1 + (k0), &lA[sl][2048 + lofs]);      \
        glds16(gB0 + (k0), &lB[sl][lofs]);             \
        glds16(gB1 + (k0), &lB[sl][2048 + lofs]);      \
    } while (0)

    const int T = K >> 5;   // 16 or 32
    ISSUE_TILE(0, 0);
    int sl = 0;
    for (int tt = 0; tt < T; ++tt) {
        asm volatile("s_waitcnt vmcnt(0)" ::: "memory");  // tile tt landed
        __builtin_amdgcn_s_barrier();                     // all waves' loads landed
        asm volatile("" ::: "memory");
        if (tt + 1 < T) ISSUE_TILE(sl ^ 1, (tt + 1) * 32);
        const ushort_t* la = lA[sl];
        const ushort_t* lb = lB[sl];
        sl ^= 1;
        bf16x8 af[4], bfr[4];
#pragma unroll
        for (int i = 0; i < 4; i++) {
            af[i]  = *(const bf16x8*)&la[(wm + i * 16 + l16) * 32 + quad * 8];
            bfr[i] = *(const bf16x8*)&lb[(wn + i * 16 + l16) * 32 + quad * 8];
        }
#pragma unroll
        for (int i = 0; i < 4; i++)
#pragma unroll
            for (int j = 0; j < 4; j++)
                acc[i][j] = __builtin_amdgcn_mfma_f32_16x16x32_bf16(af[i], bfr[j], acc[i][j], 0, 0, 0);
    }
#undef ISSUE_TILE

#pragma unroll
    for (int i = 0; i < 4; i++) {
#pragma unroll
        for (int r = 0; r < 4; r++) {
            long row = m0 + wm + i * 16 + quad * 4 + r;
#pragma unroll
            for (int j = 0; j < 4; j++) {
                int col = n0 + wn + j * 16 + l16;
                float v = acc[i][j][r] + bias[col];
                if (res) v += res[row * res_stride + col];
                if (relu) v = fmaxf(v, 0.f);
                if (out_is_f32)
                    ((float*)outp)[row * out_stride + col] = v;
                else
                    ((ushort_t*)outp)[row * out_stride + col] = f2b(v);
            }
        }
    }
}

// ---------- dilated attention: MFMA flash version ----------
// grid 1536: [0,1024): group0 (s=512,r=1,heads0-3), [1024,1536): group1
// (s=1024,r=2,off=1,heads4-7). Block = 4 waves; each wave owns 32 q-rows
// (2 m-tiles of 16); block covers 128 of the unit's 512 attended rows.
// Loop over 8 chunks of 64 keys: S = Q K^T (MFMA, keys as N), online softmax
// (shfl over l16 lanes), P -> per-wave LDS (C/D -> A layout), O += P V (MFMA,
// V^T staged in LDS with XOR-octet swizzle).
__global__ __launch_bounds__(256) void attn_kernel(const ushort_t* __restrict__ qkv,
                                                   ushort_t* __restrict__ o) {
    __shared__ __align__(16) ushort_t lK[64 * 72];       // [key][dim]
    __shared__ __align__(16) ushort_t lV[64 * 72];       // [dim][key^swz]
    __shared__ __align__(16) ushort_t lP[4 * 32 * 72];   // per-wave [qrow][key]

    const int bid = blockIdx.x;
    const int t = threadIdx.x;
    int grp, b, h, seg, qblk;
    if (bid < 1024) {
        grp = 0; qblk = bid & 3; seg = (bid >> 2) & 15; h = (bid >> 6) & 3; b = bid >> 8;
    } else {
        int u = bid - 1024;
        grp = 1; qblk = u & 3; seg = (u >> 2) & 7; h = (u >> 5) & 3; b = u >> 7;
    }
    const int habs = grp * 4 + h;
    const long segbase = (grp == 0) ? (long)seg * 512 : (long)seg * 1024 + 1;
    const int stok = 1 + grp;
    const long btok = (long)b * 8192;
    const int q0 = qblk * 128;

    const int wave = t >> 6, lane = t & 63, quad = lane >> 4, l16 = lane & 15;
    ushort_t* lPw = lP + wave * 32 * 72;

    // Q fragments: qf[m][ks], A-layout [m=l16][k=quad*8+j]
    bf16x8 qf[2][2];
#pragma unroll
    for (int m = 0; m < 2; m++) {
        long tok = btok + segbase + (long)stok * (q0 + wave * 32 + m * 16 + l16);
        const ushort_t* qp = qkv + tok * 1536 + habs * 64;
        qf[m][0] = *(const bf16x8*)(qp + quad * 8);
        qf[m][1] = *(const bf16x8*)(qp + 32 + quad * 8);
    }

    f32x4 oacc[2][4];
#pragma unroll
    for (int m = 0; m < 2; m++)
#pragma unroll
        for (int n = 0; n < 4; n++) oacc[m][n] = (f32x4){0.f, 0.f, 0.f, 0.f};
    float mst[2][4], lst[2][4];
#pragma unroll
    for (int m = 0; m < 2; m++)
#pragma unroll
        for (int r = 0; r < 4; r++) { mst[m][r] = -1e30f; lst[m][r] = 0.f; }

    const int skey = t >> 2;      // staging: key 0..63
    const int sdg = t & 3;        // dim group (16 dims)

    for (int c = 0; c < 8; c++) {
        // load K/V chunk to regs
        long ktok = btok + segbase + (long)stok * (c * 64 + skey);
        const ushort_t* kp = qkv + ktok * 1536 + 512 + habs * 64 + sdg * 16;
        s16x8 kr0 = *(const s16x8*)kp;
        s16x8 kr1 = *(const s16x8*)(kp + 8);
        s16x8 vr0 = *(const s16x8*)(kp + 512);
        s16x8 vr1 = *(const s16x8*)(kp + 520);
        __syncthreads();  // previous chunk fully consumed
        *(s16x8*)&lK[skey * 72 + sdg * 16] = kr0;
        *(s16x8*)&lK[skey * 72 + sdg * 16 + 8] = kr1;
#pragma unroll
        for (int i = 0; i < 8; i++) {
            int d0 = sdg * 16 + i, d1 = sdg * 16 + 8 + i;
            lV[d0 * 72 + (skey ^ (((d0 >> 3) & 7) * 8))] = (ushort_t)vr0[i];
            lV[d1 * 72 + (skey ^ (((d1 >> 3) & 7) * 8))] = (ushort_t)vr1[i];
        }
        __syncthreads();

        // S = Q K^T, softmax, write P
#pragma unroll
        for (int m = 0; m < 2; m++) {
            f32x4 sa[4];
#pragma unroll
            for (int n = 0; n < 4; n++) sa[n] = (f32x4){0.f, 0.f, 0.f, 0.f};
#pragma unroll
            for (int ks = 0; ks < 2; ks++)
#pragma unroll
                for (int n = 0; n < 4; n++) {
                    bf16x8 kf = *(const bf16x8*)&lK[(n * 16 + l16) * 72 + ks * 32 + quad * 8];
                    sa[n] = __builtin_amdgcn_mfma_f32_16x16x32_bf16(qf[m][ks], kf, sa[n], 0, 0, 0);
                }
#pragma unroll
            for (int r = 0; r < 4; r++) {
                float mx = fmaxf(fmaxf(sa[0][r], sa[1][r]), fmaxf(sa[2][r], sa[3][r]));
                mx = fmaxf(mx, __shfl_xor(mx, 1, 64));
                mx = fmaxf(mx, __shfl_xor(mx, 2, 64));
                mx = fmaxf(mx, __shfl_xor(mx, 4, 64));
                mx = fmaxf(mx, __shfl_xor(mx, 8, 64));
                mx *= 0.125f;
                float mold = mst[m][r];
                float mnew = fmaxf(mold, mx);
                float alpha = __expf(mold - mnew);
                float rsum = 0.f;
#pragma unroll
                for (int n = 0; n < 4; n++) {
                    float p = __expf(fmaf(sa[n][r], 0.125f, -mnew));
                    rsum += p;
                    sa[n][r] = p;
                }
                rsum += __shfl_xor(rsum, 1, 64);
                rsum += __shfl_xor(rsum, 2, 64);
                rsum += __shfl_xor(rsum, 4, 64);
                rsum += __shfl_xor(rsum, 8, 64);
                lst[m][r] = lst[m][r] * alpha + rsum;
                mst[m][r] = mnew;
#pragma unroll
                for (int n = 0; n < 4; n++) oacc[m][n][r] *= alpha;
            }
#pragma unroll
            for (int r = 0; r < 4; r++)
#pragma unroll
                for (int n = 0; n < 4; n++)
                    lPw[(m * 16 + quad * 4 + r) * 72 + n * 16 + l16] = f2b(sa[n][r]);
        }
        __asm__ volatile("s_waitcnt lgkmcnt(0)" ::: "memory");  // P visible to own wave

        // O += P V
#pragma unroll
        for (int m = 0; m < 2; m++) {
            bf16x8 pf[2];
#pragma unroll
            for (int ks = 0; ks < 2; ks++)
                pf[ks] = *(const bf16x8*)&lPw[(m * 16 + l16) * 72 + ks * 32 + quad * 8];
#pragma unroll
            for (int n = 0; n < 4; n++) {
                int shift = ((n * 2 + (l16 >> 3)) & 7) * 8;
#pragma unroll
                for (int ks = 0; ks < 2; ks++) {
                    int kcol = (ks * 32 + quad * 8) ^ shift;
                    bf16x8 vf = *(const bf16x8*)&lV[(n * 16 + l16) * 72 + kcol];
                    oacc[m][n] = __builtin_amdgcn_mfma_f32_16x16x32_bf16(pf[ks], vf, oacc[m][n], 0, 0, 0);
                }
            }
        }
    }

    // epilogue
#pragma unroll
    for (int m = 0; m < 2; m++) {
#pragma unroll
        for (int r = 0; r < 4; r++) {
            float inv = 1.f / lst[m][r];
            long tok = btok + segbase + (long)stok * (q0 + wave * 32 + m * 16 + quad * 4 + r);
            ushort_t* op = o + tok * 512 + habs * 64;
#pragma unroll
            for (int n = 0; n < 4; n++) op[n * 16 + l16] = f2b(oacc[m][n][r] * inv);
        }
    }
}

extern "C" void kernel_launch(void* const* d_in, const int* in_sizes, int n_in,
                              void* d_out, int out_size, void* d_ws, size_t ws_size,
                              hipStream_t stream) {
    const float* x    = (const float*)d_in[0];
    const float* ln1g = (const float*)d_in[1];
    const float* ln1b = (const float*)d_in[2];
    const float* Wq   = (const float*)d_in[3];
    const float* bq   = (const float*)d_in[4];
    const float* Wk   = (const float*)d_in[5];
    const float* bk   = (const float*)d_in[6];
    const float* Wv   = (const float*)d_in[7];
    const float* bv   = (const float*)d_in[8];
    const float* Wo   = (const float*)d_in[9];
    const float* bo   = (const float*)d_in[10];
    const float* ln2g = (const float*)d_in[11];
    const float* ln2b = (const float*)d_in[12];
    const float* W1   = (const float*)d_in[13];
    const float* b1   = (const float*)d_in[14];
    const float* W2   = (const float*)d_in[15];
    const float* b2   = (const float*)d_in[16];
    float* out = (float*)d_out;
    char* ws = (char*)d_ws;

    const size_t NEED = 134217728ull + 1572864 + 524288 + 1048576 + 1048576 + 8192;
    if (ws_size < NEED) return;

    ushort_t* XN    = (ushort_t*)(ws + 0);
    ushort_t* QKV   = (ushort_t*)(ws + 33554432);
    ushort_t* O     = XN;
    ushort_t* H     = XN;
    ushort_t* ACT   = QKV;
    ushort_t* WQKVT = (ushort_t*)(ws + 134217728);
    ushort_t* WOT   = WQKVT + 786432;
    ushort_t* W1T   = WOT + 262144;
    ushort_t* W2T   = W1T + 524288;
    float*    BQKV  = (float*)(W2T + 524288);

    transpose_k<<<1024, 256, 0, stream>>>(Wq, WQKVT, 512, 512);
    transpose_k<<<1024, 256, 0, stream>>>(Wk, WQKVT + 262144, 512, 512);
    transpose_k<<<1024, 256, 0, stream>>>(Wv, WQKVT + 524288, 512, 512);
    transpose_k<<<1024, 256, 0, stream>>>(Wo, WOT, 512, 512);
    transpose_k<<<2048, 256, 0, stream>>>(W1, W1T, 512, 1024);
    transpose_k<<<2048, 256, 0, stream>>>(W2, W2T, 1024, 512);
    concat3_k<<<6, 256, 0, stream>>>(bq, bk, bv, BQKV, 512);

    ln_kernel<<<32768, 256, 0, stream>>>(x + 512, 1024, ln1g, ln1b, XN, 512);
    gemm_kernel<<<3072, 256, 0, stream>>>(XN, WQKVT, BQKV, nullptr, 0,
                                          QKV, 1536, 0, 512, 0, 12);
    hipMemsetAsync(O, 0, 33554432, stream);
    attn_kernel<<<1536, 256, 0, stream>>>(QKV, O);
    gemm_kernel<<<1024, 256, 0, stream>>>(O, WOT, bo, x, 1024,
                                          out, 1024, 1, 512, 0, 4);
    ln_kernel<<<32768, 256, 0, stream>>>(out, 1024, ln2g, ln2b, H, 512);
    gemm_kernel<<<2048, 256, 0, stream>>>(H, W1T, b1, nullptr, 0,
                                          ACT, 1024, 0, 512, 1, 8);
    gemm_kernel<<<1024, 256, 0, stream>>>(ACT, W2T, b2, x + 512, 1024,
                                          out + 512, 1024, 1, 1024, 0, 4);
}

// Round 6
// 791.848 us; speedup vs baseline: 1.1158x; 1.1158x over previous
//
#include <hip/hip_runtime.h>
#include <hip/hip_bf16.h>

typedef unsigned short ushort_t;
typedef __bf16 bf16x8 __attribute__((ext_vector_type(8)));
typedef float f32x4 __attribute__((ext_vector_type(4)));
typedef short s16x8 __attribute__((ext_vector_type(8)));

__device__ __forceinline__ float b2f(ushort_t u) {
    union { unsigned u; float f; } x;
    x.u = ((unsigned)u) << 16;
    return x.f;
}
__device__ __forceinline__ ushort_t f2b(float f) {
    union { float f; unsigned u; } x;
    x.f = f;
    unsigned r = x.u + 0x7fffu + ((x.u >> 16) & 1u);
    return (ushort_t)(r >> 16);
}

// async global->LDS, 16B per lane. LDS dest must be wave-uniform base
// (HW adds lane*16); global src is per-lane.
__device__ __forceinline__ void glds16(const ushort_t* g, ushort_t* l) {
    __builtin_amdgcn_global_load_lds(
        (const __attribute__((address_space(1))) void*)g,
        (__attribute__((address_space(3))) void*)l, 16, 0, 0);
}

// ---------- transpose fp32 -> bf16: dst[C][R] = bf16(src[R][C]^T) ----------
__global__ void transpose_k(const float* __restrict__ src, ushort_t* __restrict__ dst,
                            int R, int C) {
    long i = (long)blockIdx.x * 256 + threadIdx.x;
    if (i < (long)R * C) {
        int c = (int)(i / R);
        int r = (int)(i % R);
        dst[i] = f2b(src[(long)r * C + c]);
    }
}

// ---------- concat 3 fp32 bias vectors ----------
__global__ void concat3_k(const float* a, const float* b, const float* c,
                          float* dst, int n) {
    int i = blockIdx.x * 256 + threadIdx.x;
    if (i < 3 * n) dst[i] = (i < n) ? a[i] : (i < 2 * n ? b[i - n] : c[i - 2 * n]);
}

// ---------- LayerNorm over 512 fp32 elems per row -> bf16 out ----------
__global__ __launch_bounds__(256) void ln_kernel(
    const float* __restrict__ x, long xstride,
    const float* __restrict__ g, const float* __restrict__ be,
    ushort_t* __restrict__ out, long ostride) {
    int r = blockIdx.x, t = threadIdx.x;
    const float* row = x + (long)r * xstride;
    float2 p = *(const float2*)(row + 2 * t);
    float v0 = p.x, v1 = p.y;
    float s = v0 + v1, ss = v0 * v0 + v1 * v1;
#pragma unroll
    for (int off = 32; off; off >>= 1) {
        s += __shfl_xor(s, off, 64);
        ss += __shfl_xor(ss, off, 64);
    }
    __shared__ float sb[8];
    int w = t >> 6;
    if ((t & 63) == 0) { sb[w] = s; sb[4 + w] = ss; }
    __syncthreads();
    s = sb[0] + sb[1] + sb[2] + sb[3];
    ss = sb[4] + sb[5] + sb[6] + sb[7];
    float mean = s * (1.f / 512.f);
    float var = ss * (1.f / 512.f) - mean * mean;
    float rstd = rsqrtf(var + 1e-5f);
    float2 gp = *(const float2*)(g + 2 * t);
    float2 bp = *(const float2*)(be + 2 * t);
    ushort2 q;
    q.x = f2b((v0 - mean) * rstd * gp.x + bp.x);
    q.y = f2b((v1 - mean) * rstd * gp.y + bp.y);
    *(ushort2*)(out + (long)r * ostride + 2 * t) = q;
}

// ---------- MFMA GEMM: C[M,N] = A[M,K](bf16) * Bt[N,K](bf16)^T + bias(f32)
//            (+ res(f32)) (+relu); out bf16 or fp32 ----------
// r5 theory: per-CU fill rate is MSHR-capped at ~5.6 B/cy regardless of
// schedule/occupancy (r0-r4 all neutral). Lever = FILL BYTES PER FLOP:
// 256x256 tile, BK=32 -> 128 FLOP/B (2x the 128x128 tile) => per-CU staged
// bytes halve. 512 thr = 8 waves (2m x 4n), wave tile 128x64, acc[8][4].
// LDS 64KB dbuf, depth-1 glds prefetch (fill pipe stays saturated).
// 16B-chunk XOR swizzle (chunk ^= row&3) applied to BOTH the glds global
// source and the ds_read offset (rule: both-sides-or-neither) cuts the
// fragment-read bank conflict 8-way -> 4-way.
__global__ __launch_bounds__(512, 2) void gemm_kernel(
    const ushort_t* __restrict__ A, const ushort_t* __restrict__ Bt,
    const float* __restrict__ bias,
    const float* __restrict__ res, long res_stride,
    void* __restrict__ outp, long out_stride, int out_is_f32,
    int K, int relu, int nTiles) {
    __shared__ __align__(16) ushort_t lA[2][256 * 32];
    __shared__ __align__(16) ushort_t lB[2][256 * 32];
    const int t = threadIdx.x;
    // XCD-aware remap (grid % 8 == 0, bijective): xcd owns contiguous
    // m-range, n fastest -> same-XCD blocks reuse one A-panel per L2.
    const int bid = blockIdx.x;
    const int xcd = bid & 7;
    const int jj = bid >> 3;
    const int mPerXcd = (int)gridDim.x / (nTiles * 8);
    const int mt = xcd * mPerXcd + jj / nTiles;
    const int nt = jj % nTiles;
    const int m0 = mt * 256, n0 = nt * 256;

    const int wave = t >> 6, lane = t & 63, quad = lane >> 4, l16 = lane & 15;
    const int wm = (wave & 1) * 128, wn = (wave >> 1) * 64;
    f32x4 acc[8][4];
#pragma unroll
    for (int i = 0; i < 8; i++)
#pragma unroll
        for (int j = 0; j < 4; j++) acc[i][j] = (f32x4){0.f, 0.f, 0.f, 0.f};

    // staging: thread t writes LDS bytes [t*16, t*16+16) per 8KB half-tile
    // => tile row = t>>2 (+128 for 2nd half), 16B chunk = t&3. Global source
    // chunk is XOR-swizzled: phys chunk (t&3) holds logical (t&3)^(row&3).
    const int srow = t >> 2;                       // 0..127
    const int swz = ((t & 3) ^ (srow & 3)) * 8;    // swizzled elem offset
    const ushort_t* gA0 = A + (long)(m0 + srow) * K + swz;
    const ushort_t* gA1 = A + (long)(m0 + 128 + srow) * K + swz;   // (row+128)&3 == row&3
    const ushort_t* gB0 = Bt + (long)(n0 + srow) * K + swz;
    const ushort_t* gB1 = Bt + (long)(n0 + 128 + srow) * K + swz;
    const int lofs = wave * 512;   // wave-uniform base (HW adds lane*16B)

#define ISSUE_TILE(sl, k0)                             \
    do {                                               \
        glds16(gA0 + (k0), &lA[sl][lofs]);             \
        glds16(gA1 + (k0), &lA[sl][4096 + lofs]);      \
        glds16(gB0 + (k0), &lB[sl][lofs]);             \
        glds16(gB1 + (k0), &lB[sl][4096 + lofs]);      \
    } while (0)

    const int T = K >> 5;   // 16 or 32
    ISSUE_TILE(0, 0);
    int sl = 0;
    for (int tt = 0; tt < T; ++tt) {
        asm volatile("s_waitcnt vmcnt(0)" ::: "memory");  // tile tt landed
        __builtin_amdgcn_s_barrier();                     // all waves' loads landed
        asm volatile("" ::: "memory");
        if (tt + 1 < T) ISSUE_TILE(sl ^ 1, (tt + 1) * 32);
        const ushort_t* la = lA[sl];
        const ushort_t* lb = lB[sl];
        sl ^= 1;
        // fragment reads: logical chunk quad of row r lives at phys chunk
        // quad^(r&3); r&3 == l16&3 for all fragment rows (wm,wn,16i = 0 mod 4)
        const int pch = (quad ^ (l16 & 3)) * 8;
        bf16x8 af[8], bfr[4];
#pragma unroll
        for (int i = 0; i < 8; i++)
            af[i] = *(const bf16x8*)&la[(wm + i * 16 + l16) * 32 + pch];
#pragma unroll
        for (int j = 0; j < 4; j++)
            bfr[j] = *(const bf16x8*)&lb[(wn + j * 16 + l16) * 32 + pch];
#pragma unroll
        for (int i = 0; i < 8; i++)
#pragma unroll
            for (int j = 0; j < 4; j++)
                acc[i][j] = __builtin_amdgcn_mfma_f32_16x16x32_bf16(af[i], bfr[j], acc[i][j], 0, 0, 0);
    }
#undef ISSUE_TILE

#pragma unroll
    for (int i = 0; i < 8; i++) {
#pragma unroll
        for (int r = 0; r < 4; r++) {
            long row = m0 + wm + i * 16 + quad * 4 + r;
#pragma unroll
            for (int j = 0; j < 4; j++) {
                int col = n0 + wn + j * 16 + l16;
                float v = acc[i][j][r] + bias[col];
                if (res) v += res[row * res_stride + col];
                if (relu) v = fmaxf(v, 0.f);
                if (out_is_f32)
                    ((float*)outp)[row * out_stride + col] = v;
                else
                    ((ushort_t*)outp)[row * out_stride + col] = f2b(v);
            }
        }
    }
}

// ---------- dilated attention: MFMA flash version ----------
// grid 1536: [0,1024): group0 (s=512,r=1,heads0-3), [1024,1536): group1
// (s=1024,r=2,off=1,heads4-7). Block = 4 waves; each wave owns 32 q-rows
// (2 m-tiles of 16); block covers 128 of the unit's 512 attended rows.
// Loop over 8 chunks of 64 keys: S = Q K^T (MFMA, keys as N), online softmax
// (shfl over l16 lanes), P -> per-wave LDS (C/D -> A layout), O += P V (MFMA,
// V^T staged in LDS with XOR-octet swizzle).
__global__ __launch_bounds__(256) void attn_kernel(const ushort_t* __restrict__ qkv,
                                                   ushort_t* __restrict__ o) {
    __shared__ __align__(16) ushort_t lK[64 * 72];       // [key][dim]
    __shared__ __align__(16) ushort_t lV[64 * 72];       // [dim][key^swz]
    __shared__ __align__(16) ushort_t lP[4 * 32 * 72];   // per-wave [qrow][key]

    const int bid = blockIdx.x;
    const int t = threadIdx.x;
    int grp, b, h, seg, qblk;
    if (bid < 1024) {
        grp = 0; qblk = bid & 3; seg = (bid >> 2) & 15; h = (bid >> 6) & 3; b = bid >> 8;
    } else {
        int u = bid - 1024;
        grp = 1; qblk = u & 3; seg = (u >> 2) & 7; h = (u >> 5) & 3; b = u >> 7;
    }
    const int habs = grp * 4 + h;
    const long segbase = (grp == 0) ? (long)seg * 512 : (long)seg * 1024 + 1;
    const int stok = 1 + grp;
    const long btok = (long)b * 8192;
    const int q0 = qblk * 128;

    const int wave = t >> 6, lane = t & 63, quad = lane >> 4, l16 = lane & 15;
    ushort_t* lPw = lP + wave * 32 * 72;

    // Q fragments: qf[m][ks], A-layout [m=l16][k=quad*8+j]
    bf16x8 qf[2][2];
#pragma unroll
    for (int m = 0; m < 2; m++) {
        long tok = btok + segbase + (long)stok * (q0 + wave * 32 + m * 16 + l16);
        const ushort_t* qp = qkv + tok * 1536 + habs * 64;
        qf[m][0] = *(const bf16x8*)(qp + quad * 8);
        qf[m][1] = *(const bf16x8*)(qp + 32 + quad * 8);
    }

    f32x4 oacc[2][4];
#pragma unroll
    for (int m = 0; m < 2; m++)
#pragma unroll
        for (int n = 0; n < 4; n++) oacc[m][n] = (f32x4){0.f, 0.f, 0.f, 0.f};
    float mst[2][4], lst[2][4];
#pragma unroll
    for (int m = 0; m < 2; m++)
#pragma unroll
        for (int r = 0; r < 4; r++) { mst[m][r] = -1e30f; lst[m][r] = 0.f; }

    const int skey = t >> 2;      // staging: key 0..63
    const int sdg = t & 3;        // dim group (16 dims)

    for (int c = 0; c < 8; c++) {
        // load K/V chunk to regs
        long ktok = btok + segbase + (long)stok * (c * 64 + skey);
        const ushort_t* kp = qkv + ktok * 1536 + 512 + habs * 64 + sdg * 16;
        s16x8 kr0 = *(const s16x8*)kp;
        s16x8 kr1 = *(const s16x8*)(kp + 8);
        s16x8 vr0 = *(const s16x8*)(kp + 512);
        s16x8 vr1 = *(const s16x8*)(kp + 520);
        __syncthreads();  // previous chunk fully consumed
        *(s16x8*)&lK[skey * 72 + sdg * 16] = kr0;
        *(s16x8*)&lK[skey * 72 + sdg * 16 + 8] = kr1;
#pragma unroll
        for (int i = 0; i < 8; i++) {
            int d0 = sdg * 16 + i, d1 = sdg * 16 + 8 + i;
            lV[d0 * 72 + (skey ^ (((d0 >> 3) & 7) * 8))] = (ushort_t)vr0[i];
            lV[d1 * 72 + (skey ^ (((d1 >> 3) & 7) * 8))] = (ushort_t)vr1[i];
        }
        __syncthreads();

        // S = Q K^T, softmax, write P
#pragma unroll
        for (int m = 0; m < 2; m++) {
            f32x4 sa[4];
#pragma unroll
            for (int n = 0; n < 4; n++) sa[n] = (f32x4){0.f, 0.f, 0.f, 0.f};
#pragma unroll
            for (int ks = 0; ks < 2; ks++)
#pragma unroll
                for (int n = 0; n < 4; n++) {
                    bf16x8 kf = *(const bf16x8*)&lK[(n * 16 + l16) * 72 + ks * 32 + quad * 8];
                    sa[n] = __builtin_amdgcn_mfma_f32_16x16x32_bf16(qf[m][ks], kf, sa[n], 0, 0, 0);
                }
#pragma unroll
            for (int r = 0; r < 4; r++) {
                float mx = fmaxf(fmaxf(sa[0][r], sa[1][r]), fmaxf(sa[2][r], sa[3][r]));
                mx = fmaxf(mx, __shfl_xor(mx, 1, 64));
                mx = fmaxf(mx, __shfl_xor(mx, 2, 64));
                mx = fmaxf(mx, __shfl_xor(mx, 4, 64));
                mx = fmaxf(mx, __shfl_xor(mx, 8, 64));
                mx *= 0.125f;
                float mold = mst[m][r];
                float mnew = fmaxf(mold, mx);
                float alpha = __expf(mold - mnew);
                float rsum = 0.f;
#pragma unroll
                for (int n = 0; n < 4; n++) {
                    float p = __expf(fmaf(sa[n][r], 0.125f, -mnew));
                    rsum += p;
                    sa[n][r] = p;
                }
                rsum += __shfl_xor(rsum, 1, 64);
                rsum += __shfl_xor(rsum, 2, 64);
                rsum += __shfl_xor(rsum, 4, 64);
                rsum += __shfl_xor(rsum, 8, 64);
                lst[m][r] = lst[m][r] * alpha + rsum;
                mst[m][r] = mnew;
#pragma unroll
                for (int n = 0; n < 4; n++) oacc[m][n][r] *= alpha;
            }
#pragma unroll
            for (int r = 0; r < 4; r++)
#pragma unroll
                for (int n = 0; n < 4; n++)
                    lPw[(m * 16 + quad * 4 + r) * 72 + n * 16 + l16] = f2b(sa[n][r]);
        }
        __asm__ volatile("s_waitcnt lgkmcnt(0)" ::: "memory");  // P visible to own wave

        // O += P V
#pragma unroll
        for (int m = 0; m < 2; m++) {
            bf16x8 pf[2];
#pragma unroll
            for (int ks = 0; ks < 2; ks++)
                pf[ks] = *(const bf16x8*)&lPw[(m * 16 + l16) * 72 + ks * 32 + quad * 8];
#pragma unroll
            for (int n = 0; n < 4; n++) {
                int shift = ((n * 2 + (l16 >> 3)) & 7) * 8;
#pragma unroll
                for (int ks = 0; ks < 2; ks++) {
                    int kcol = (ks * 32 + quad * 8) ^ shift;
                    bf16x8 vf = *(const bf16x8*)&lV[(n * 16 + l16) * 72 + kcol];
                    oacc[m][n] = __builtin_amdgcn_mfma_f32_16x16x32_bf16(pf[ks], vf, oacc[m][n], 0, 0, 0);
                }
            }
        }
    }

    // epilogue
#pragma unroll
    for (int m = 0; m < 2; m++) {
#pragma unroll
        for (int r = 0; r < 4; r++) {
            float inv = 1.f / lst[m][r];
            long tok = btok + segbase + (long)stok * (q0 + wave * 32 + m * 16 + quad * 4 + r);
            ushort_t* op = o + tok * 512 + habs * 64;
#pragma unroll
            for (int n = 0; n < 4; n++) op[n * 16 + l16] = f2b(oacc[m][n][r] * inv);
        }
    }
}

extern "C" void kernel_launch(void* const* d_in, const int* in_sizes, int n_in,
                              void* d_out, int out_size, void* d_ws, size_t ws_size,
                              hipStream_t stream) {
    const float* x    = (const float*)d_in[0];
    const float* ln1g = (const float*)d_in[1];
    const float* ln1b = (const float*)d_in[2];
    const float* Wq   = (const float*)d_in[3];
    const float* bq   = (const float*)d_in[4];
    const float* Wk   = (const float*)d_in[5];
    const float* bk   = (const float*)d_in[6];
    const float* Wv   = (const float*)d_in[7];
    const float* bv   = (const float*)d_in[8];
    const float* Wo   = (const float*)d_in[9];
    const float* bo   = (const float*)d_in[10];
    const float* ln2g = (const float*)d_in[11];
    const float* ln2b = (const float*)d_in[12];
    const float* W1   = (const float*)d_in[13];
    const float* b1   = (const float*)d_in[14];
    const float* W2   = (const float*)d_in[15];
    const float* b2   = (const float*)d_in[16];
    float* out = (float*)d_out;
    char* ws = (char*)d_ws;

    const size_t NEED = 134217728ull + 1572864 + 524288 + 1048576 + 1048576 + 8192;
    if (ws_size < NEED) return;

    ushort_t* XN    = (ushort_t*)(ws + 0);
    ushort_t* QKV   = (ushort_t*)(ws + 33554432);
    ushort_t* O     = XN;
    ushort_t* H     = XN;
    ushort_t* ACT   = QKV;
    ushort_t* WQKVT = (ushort_t*)(ws + 134217728);
    ushort_t* WOT   = WQKVT + 786432;
    ushort_t* W1T   = WOT + 262144;
    ushort_t* W2T   = W1T + 524288;
    float*    BQKV  = (float*)(W2T + 524288);

    transpose_k<<<1024, 256, 0, stream>>>(Wq, WQKVT, 512, 512);
    transpose_k<<<1024, 256, 0, stream>>>(Wk, WQKVT + 262144, 512, 512);
    transpose_k<<<1024, 256, 0, stream>>>(Wv, WQKVT + 524288, 512, 512);
    transpose_k<<<1024, 256, 0, stream>>>(Wo, WOT, 512, 512);
    transpose_k<<<2048, 256, 0, stream>>>(W1, W1T, 512, 1024);
    transpose_k<<<2048, 256, 0, stream>>>(W2, W2T, 1024, 512);
    concat3_k<<<6, 256, 0, stream>>>(bq, bk, bv, BQKV, 512);

    ln_kernel<<<32768, 256, 0, stream>>>(x + 512, 1024, ln1g, ln1b, XN, 512);
    gemm_kernel<<<768, 512, 0, stream>>>(XN, WQKVT, BQKV, nullptr, 0,
                                         QKV, 1536, 0, 512, 0, 6);
    hipMemsetAsync(O, 0, 33554432, stream);
    attn_kernel<<<1536, 256, 0, stream>>>(QKV, O);
    gemm_kernel<<<256, 512, 0, stream>>>(O, WOT, bo, x, 1024,
                                         out, 1024, 1, 512, 0, 2);
    ln_kernel<<<32768, 256, 0, stream>>>(out, 1024, ln2g, ln2b, H, 512);
    gemm_kernel<<<512, 512, 0, stream>>>(H, W1T, b1, nullptr, 0,
                                         ACT, 1024, 0, 512, 1, 4);
    gemm_kernel<<<256, 512, 0, stream>>>(ACT, W2T, b2, x + 512, 1024,
                                         out + 512, 1024, 1, 1024, 0, 2);
}

// Round 7
// 673.717 us; speedup vs baseline: 1.3115x; 1.1753x over previous
//
#include <hip/hip_runtime.h>
#include <hip/hip_bf16.h>

typedef unsigned short ushort_t;
typedef __bf16 bf16x8 __attribute__((ext_vector_type(8)));
typedef float f32x4 __attribute__((ext_vector_type(4)));
typedef short s16x8 __attribute__((ext_vector_type(8)));

__device__ __forceinline__ float b2f(ushort_t u) {
    union { unsigned u; float f; } x;
    x.u = ((unsigned)u) << 16;
    return x.f;
}
__device__ __forceinline__ ushort_t f2b(float f) {
    union { float f; unsigned u; } x;
    x.f = f;
    unsigned r = x.u + 0x7fffu + ((x.u >> 16) & 1u);
    return (ushort_t)(r >> 16);
}

// ---------- transpose fp32 -> bf16: dst[C][R] = bf16(src[R][C]^T) ----------
__global__ void transpose_k(const float* __restrict__ src, ushort_t* __restrict__ dst,
                            int R, int C) {
    long i = (long)blockIdx.x * 256 + threadIdx.x;
    if (i < (long)R * C) {
        int c = (int)(i / R);
        int r = (int)(i % R);
        dst[i] = f2b(src[(long)r * C + c]);
    }
}

// ---------- concat 3 fp32 bias vectors ----------
__global__ void concat3_k(const float* a, const float* b, const float* c,
                          float* dst, int n) {
    int i = blockIdx.x * 256 + threadIdx.x;
    if (i < 3 * n) dst[i] = (i < n) ? a[i] : (i < 2 * n ? b[i - n] : c[i - 2 * n]);
}

// ---------- LayerNorm over 512 fp32 elems per row -> bf16 out ----------
__global__ __launch_bounds__(256) void ln_kernel(
    const float* __restrict__ x, long xstride,
    const float* __restrict__ g, const float* __restrict__ be,
    ushort_t* __restrict__ out, long ostride) {
    int r = blockIdx.x, t = threadIdx.x;
    const float* row = x + (long)r * xstride;
    float2 p = *(const float2*)(row + 2 * t);
    float v0 = p.x, v1 = p.y;
    float s = v0 + v1, ss = v0 * v0 + v1 * v1;
#pragma unroll
    for (int off = 32; off; off >>= 1) {
        s += __shfl_xor(s, off, 64);
        ss += __shfl_xor(ss, off, 64);
    }
    __shared__ float sb[8];
    int w = t >> 6;
    if ((t & 63) == 0) { sb[w] = s; sb[4 + w] = ss; }
    __syncthreads();
    s = sb[0] + sb[1] + sb[2] + sb[3];
    ss = sb[4] + sb[5] + sb[6] + sb[7];
    float mean = s * (1.f / 512.f);
    float var = ss * (1.f / 512.f) - mean * mean;
    float rstd = rsqrtf(var + 1e-5f);
    float2 gp = *(const float2*)(g + 2 * t);
    float2 bp = *(const float2*)(be + 2 * t);
    ushort2 q;
    q.x = f2b((v0 - mean) * rstd * gp.x + bp.x);
    q.y = f2b((v1 - mean) * rstd * gp.y + bp.y);
    *(ushort2*)(out + (long)r * ostride + 2 * t) = q;
}

// ---------- MFMA GEMM: C[M,N] = A[M,K](bf16) * Bt[N,K](bf16)^T + bias(f32)
//            (+ res(f32)) (+relu); out bf16 or fp32 ----------
// r6 theory: per-CU fill rate tracks waves/CU (per-wave vmem concurrency is
// the limiter). Design: 256x128 tile (grid >= 512 on all GEMMs => 2+
// blocks/CU), SINGLE-buffer LDS (24KB) + T14 reg-staging: tile t+1's global
// loads are issued into REGISTERS right after tile t's LDS write and stay in
// flight across the whole compute phase (no vmcnt(0) convoy, only data-dep
// waits). Raw s_barrier + lgkmcnt(0) only -- __syncthreads would drain the
// in-flight loads. __launch_bounds__(512,4) forces VGPR<=128 => 16 waves/CU.
// 16B-chunk XOR swizzle (chunk ^= row&3) on ds_write and frag ds_read.
__global__ __launch_bounds__(512, 4) void gemm_kernel(
    const ushort_t* __restrict__ A, const ushort_t* __restrict__ Bt,
    const float* __restrict__ bias,
    const float* __restrict__ res, long res_stride,
    void* __restrict__ outp, long out_stride, int out_is_f32,
    int K, int relu, int nTiles) {
    __shared__ __align__(16) ushort_t lA[256 * 32];   // 16KB
    __shared__ __align__(16) ushort_t lB[128 * 32];   // 8KB
    const int t = threadIdx.x;
    // XCD-aware bijective remap: xcd owns a contiguous m-range, n fastest.
    const int bid = blockIdx.x;
    const int xcd = bid & 7;
    const int jj = bid >> 3;
    const int mPerXcd = (int)gridDim.x / (nTiles * 8);
    const int mt = xcd * mPerXcd + jj / nTiles;
    const int nt = jj % nTiles;
    const int m0 = mt * 256, n0 = nt * 128;

    const int wave = t >> 6, lane = t & 63, quad = lane >> 4, l16 = lane & 15;
    const int wm = (wave & 1) * 128, wn = (wave >> 1) * 32;
    f32x4 acc[8][2];
#pragma unroll
    for (int i = 0; i < 8; i++)
#pragma unroll
        for (int j = 0; j < 2; j++) acc[i][j] = (f32x4){0.f, 0.f, 0.f, 0.f};

    // staging map: thread t owns row r = t>>2 (and r+128 for A's 2nd half),
    // 16B logical chunk l = t&3; LDS phys chunk = l ^ (r&3) (bank swizzle).
    const int sr = t >> 2;               // 0..127
    const int sc = t & 3;                // logical chunk
    const int pc = (sc ^ (sr & 3)) * 8;  // phys elem offset in LDS row
    const ushort_t* gA0 = A + (long)(m0 + sr) * K + sc * 8;
    const ushort_t* gA1 = A + (long)(m0 + 128 + sr) * K + sc * 8;
    const ushort_t* gB0 = Bt + (long)(n0 + sr) * K + sc * 8;
    ushort_t* wA0 = &lA[sr * 32 + pc];
    ushort_t* wA1 = &lA[(128 + sr) * 32 + pc];
    ushort_t* wB0 = &lB[sr * 32 + pc];

    const int T = K >> 5;   // 16 or 32
    s16x8 va0 = *(const s16x8*)gA0;
    s16x8 va1 = *(const s16x8*)gA1;
    s16x8 vb0 = *(const s16x8*)gB0;

    // frag-read phys chunk: logical chunk 'quad' of row (..+l16) is at
    // quad ^ (l16&3)  (row bases are multiples of 16).
    const int pch = (quad ^ (l16 & 3)) * 8;

    for (int tt = 0; tt < T; ++tt) {
        __builtin_amdgcn_s_barrier();    // all waves done reading prev tile
        // stage tile tt from regs (compiler inserts vmcnt waits on deps)
        *(s16x8*)wA0 = va0;
        *(s16x8*)wA1 = va1;
        *(s16x8*)wB0 = vb0;
        // issue tile tt+1 loads now; they fly during the whole compute phase
        if (tt + 1 < T) {
            int k0 = (tt + 1) * 32;
            va0 = *(const s16x8*)(gA0 + k0);
            va1 = *(const s16x8*)(gA1 + k0);
            vb0 = *(const s16x8*)(gB0 + k0);
        }
        asm volatile("s_waitcnt lgkmcnt(0)" ::: "memory");  // ds_writes done
        __builtin_amdgcn_s_barrier();    // tile tt visible to all waves
        bf16x8 bfr0 = *(const bf16x8*)&lB[(wn + l16) * 32 + pch];
        bf16x8 bfr1 = *(const bf16x8*)&lB[(wn + 16 + l16) * 32 + pch];
#pragma unroll
        for (int i = 0; i < 8; i++) {
            bf16x8 afv = *(const bf16x8*)&lA[(wm + i * 16 + l16) * 32 + pch];
            acc[i][0] = __builtin_amdgcn_mfma_f32_16x16x32_bf16(afv, bfr0, acc[i][0], 0, 0, 0);
            acc[i][1] = __builtin_amdgcn_mfma_f32_16x16x32_bf16(afv, bfr1, acc[i][1], 0, 0, 0);
        }
    }

#pragma unroll
    for (int i = 0; i < 8; i++) {
#pragma unroll
        for (int r = 0; r < 4; r++) {
            long row = m0 + wm + i * 16 + quad * 4 + r;
#pragma unroll
            for (int j = 0; j < 2; j++) {
                int col = n0 + wn + j * 16 + l16;
                float v = acc[i][j][r] + bias[col];
                if (res) v += res[row * res_stride + col];
                if (relu) v = fmaxf(v, 0.f);
                if (out_is_f32)
                    ((float*)outp)[row * out_stride + col] = v;
                else
                    ((ushort_t*)outp)[row * out_stride + col] = f2b(v);
            }
        }
    }
}

// ---------- dilated attention: MFMA flash version ----------
// grid 1536: [0,1024): group0 (s=512,r=1,heads0-3), [1024,1536): group1
// (s=1024,r=2,off=1,heads4-7). Block = 4 waves; each wave owns 32 q-rows
// (2 m-tiles of 16); block covers 128 of the unit's 512 attended rows.
// Loop over 8 chunks of 64 keys: S = Q K^T (MFMA, keys as N), online softmax
// (shfl over l16 lanes), P -> per-wave LDS (C/D -> A layout), O += P V (MFMA,
// V^T staged in LDS with XOR-octet swizzle).
__global__ __launch_bounds__(256) void attn_kernel(const ushort_t* __restrict__ qkv,
                                                   ushort_t* __restrict__ o) {
    __shared__ __align__(16) ushort_t lK[64 * 72];       // [key][dim]
    __shared__ __align__(16) ushort_t lV[64 * 72];       // [dim][key^swz]
    __shared__ __align__(16) ushort_t lP[4 * 32 * 72];   // per-wave [qrow][key]

    const int bid = blockIdx.x;
    const int t = threadIdx.x;
    int grp, b, h, seg, qblk;
    if (bid < 1024) {
        grp = 0; qblk = bid & 3; seg = (bid >> 2) & 15; h = (bid >> 6) & 3; b = bid >> 8;
    } else {
        int u = bid - 1024;
        grp = 1; qblk = u & 3; seg = (u >> 2) & 7; h = (u >> 5) & 3; b = u >> 7;
    }
    const int habs = grp * 4 + h;
    const long segbase = (grp == 0) ? (long)seg * 512 : (long)seg * 1024 + 1;
    const int stok = 1 + grp;
    const long btok = (long)b * 8192;
    const int q0 = qblk * 128;

    const int wave = t >> 6, lane = t & 63, quad = lane >> 4, l16 = lane & 15;
    ushort_t* lPw = lP + wave * 32 * 72;

    // Q fragments: qf[m][ks], A-layout [m=l16][k=quad*8+j]
    bf16x8 qf[2][2];
#pragma unroll
    for (int m = 0; m < 2; m++) {
        long tok = btok + segbase + (long)stok * (q0 + wave * 32 + m * 16 + l16);
        const ushort_t* qp = qkv + tok * 1536 + habs * 64;
        qf[m][0] = *(const bf16x8*)(qp + quad * 8);
        qf[m][1] = *(const bf16x8*)(qp + 32 + quad * 8);
    }

    f32x4 oacc[2][4];
#pragma unroll
    for (int m = 0; m < 2; m++)
#pragma unroll
        for (int n = 0; n < 4; n++) oacc[m][n] = (f32x4){0.f, 0.f, 0.f, 0.f};
    float mst[2][4], lst[2][4];
#pragma unroll
    for (int m = 0; m < 2; m++)
#pragma unroll
        for (int r = 0; r < 4; r++) { mst[m][r] = -1e30f; lst[m][r] = 0.f; }

    const int skey = t >> 2;      // staging: key 0..63
    const int sdg = t & 3;        // dim group (16 dims)

    for (int c = 0; c < 8; c++) {
        // load K/V chunk to regs
        long ktok = btok + segbase + (long)stok * (c * 64 + skey);
        const ushort_t* kp = qkv + ktok * 1536 + 512 + habs * 64 + sdg * 16;
        s16x8 kr0 = *(const s16x8*)kp;
        s16x8 kr1 = *(const s16x8*)(kp + 8);
        s16x8 vr0 = *(const s16x8*)(kp + 512);
        s16x8 vr1 = *(const s16x8*)(kp + 520);
        __syncthreads();  // previous chunk fully consumed
        *(s16x8*)&lK[skey * 72 + sdg * 16] = kr0;
        *(s16x8*)&lK[skey * 72 + sdg * 16 + 8] = kr1;
#pragma unroll
        for (int i = 0; i < 8; i++) {
            int d0 = sdg * 16 + i, d1 = sdg * 16 + 8 + i;
            lV[d0 * 72 + (skey ^ (((d0 >> 3) & 7) * 8))] = (ushort_t)vr0[i];
            lV[d1 * 72 + (skey ^ (((d1 >> 3) & 7) * 8))] = (ushort_t)vr1[i];
        }
        __syncthreads();

        // S = Q K^T, softmax, write P
#pragma unroll
        for (int m = 0; m < 2; m++) {
            f32x4 sa[4];
#pragma unroll
            for (int n = 0; n < 4; n++) sa[n] = (f32x4){0.f, 0.f, 0.f, 0.f};
#pragma unroll
            for (int ks = 0; ks < 2; ks++)
#pragma unroll
                for (int n = 0; n < 4; n++) {
                    bf16x8 kf = *(const bf16x8*)&lK[(n * 16 + l16) * 72 + ks * 32 + quad * 8];
                    sa[n] = __builtin_amdgcn_mfma_f32_16x16x32_bf16(qf[m][ks], kf, sa[n], 0, 0, 0);
                }
#pragma unroll
            for (int r = 0; r < 4; r++) {
                float mx = fmaxf(fmaxf(sa[0][r], sa[1][r]), fmaxf(sa[2][r], sa[3][r]));
                mx = fmaxf(mx, __shfl_xor(mx, 1, 64));
                mx = fmaxf(mx, __shfl_xor(mx, 2, 64));
                mx = fmaxf(mx, __shfl_xor(mx, 4, 64));
                mx = fmaxf(mx, __shfl_xor(mx, 8, 64));
                mx *= 0.125f;
                float mold = mst[m][r];
                float mnew = fmaxf(mold, mx);
                float alpha = __expf(mold - mnew);
                float rsum = 0.f;
#pragma unroll
                for (int n = 0; n < 4; n++) {
                    float p = __expf(fmaf(sa[n][r], 0.125f, -mnew));
                    rsum += p;
                    sa[n][r] = p;
                }
                rsum += __shfl_xor(rsum, 1, 64);
                rsum += __shfl_xor(rsum, 2, 64);
                rsum += __shfl_xor(rsum, 4, 64);
                rsum += __shfl_xor(rsum, 8, 64);
                lst[m][r] = lst[m][r] * alpha + rsum;
                mst[m][r] = mnew;
#pragma unroll
                for (int n = 0; n < 4; n++) oacc[m][n][r] *= alpha;
            }
#pragma unroll
            for (int r = 0; r < 4; r++)
#pragma unroll
                for (int n = 0; n < 4; n++)
                    lPw[(m * 16 + quad * 4 + r) * 72 + n * 16 + l16] = f2b(sa[n][r]);
        }
        __asm__ volatile("s_waitcnt lgkmcnt(0)" ::: "memory");  // P visible to own wave

        // O += P V
#pragma unroll
        for (int m = 0; m < 2; m++) {
            bf16x8 pf[2];
#pragma unroll
            for (int ks = 0; ks < 2; ks++)
                pf[ks] = *(const bf16x8*)&lPw[(m * 16 + l16) * 72 + ks * 32 + quad * 8];
#pragma unroll
            for (int n = 0; n < 4; n++) {
                int shift = ((n * 2 + (l16 >> 3)) & 7) * 8;
#pragma unroll
                for (int ks = 0; ks < 2; ks++) {
                    int kcol = (ks * 32 + quad * 8) ^ shift;
                    bf16x8 vf = *(const bf16x8*)&lV[(n * 16 + l16) * 72 + kcol];
                    oacc[m][n] = __builtin_amdgcn_mfma_f32_16x16x32_bf16(pf[ks], vf, oacc[m][n], 0, 0, 0);
                }
            }
        }
    }

    // epilogue
#pragma unroll
    for (int m = 0; m < 2; m++) {
#pragma unroll
        for (int r = 0; r < 4; r++) {
            float inv = 1.f / lst[m][r];
            long tok = btok + segbase + (long)stok * (q0 + wave * 32 + m * 16 + quad * 4 + r);
            ushort_t* op = o + tok * 512 + habs * 64;
#pragma unroll
            for (int n = 0; n < 4; n++) op[n * 16 + l16] = f2b(oacc[m][n][r] * inv);
        }
    }
}

extern "C" void kernel_launch(void* const* d_in, const int* in_sizes, int n_in,
                              void* d_out, int out_size, void* d_ws, size_t ws_size,
                              hipStream_t stream) {
    const float* x    = (const float*)d_in[0];
    const float* ln1g = (const float*)d_in[1];
    const float* ln1b = (const float*)d_in[2];
    const float* Wq   = (const float*)d_in[3];
    const float* bq   = (const float*)d_in[4];
    const float* Wk   = (const float*)d_in[5];
    const float* bk   = (const float*)d_in[6];
    const float* Wv   = (const float*)d_in[7];
    const float* bv   = (const float*)d_in[8];
    const float* Wo   = (const float*)d_in[9];
    const float* bo   = (const float*)d_in[10];
    const float* ln2g = (const float*)d_in[11];
    const float* ln2b = (const float*)d_in[12];
    const float* W1   = (const float*)d_in[13];
    const float* b1   = (const float*)d_in[14];
    const float* W2   = (const float*)d_in[15];
    const float* b2   = (const float*)d_in[16];
    float* out = (float*)d_out;
    char* ws = (char*)d_ws;

    const size_t NEED = 134217728ull + 1572864 + 524288 + 1048576 + 1048576 + 8192;
    if (ws_size < NEED) return;

    ushort_t* XN    = (ushort_t*)(ws + 0);
    ushort_t* QKV   = (ushort_t*)(ws + 33554432);
    ushort_t* O     = XN;
    ushort_t* H     = XN;
    ushort_t* ACT   = QKV;
    ushort_t* WQKVT = (ushort_t*)(ws + 134217728);
    ushort_t* WOT   = WQKVT + 786432;
    ushort_t* W1T   = WOT + 262144;
    ushort_t* W2T   = W1T + 524288;
    float*    BQKV  = (float*)(W2T + 524288);

    transpose_k<<<1024, 256, 0, stream>>>(Wq, WQKVT, 512, 512);
    transpose_k<<<1024, 256, 0, stream>>>(Wk, WQKVT + 262144, 512, 512);
    transpose_k<<<1024, 256, 0, stream>>>(Wv, WQKVT + 524288, 512, 512);
    transpose_k<<<1024, 256, 0, stream>>>(Wo, WOT, 512, 512);
    transpose_k<<<2048, 256, 0, stream>>>(W1, W1T, 512, 1024);
    transpose_k<<<2048, 256, 0, stream>>>(W2, W2T, 1024, 512);
    concat3_k<<<6, 256, 0, stream>>>(bq, bk, bv, BQKV, 512);

    ln_kernel<<<32768, 256, 0, stream>>>(x + 512, 1024, ln1g, ln1b, XN, 512);
    gemm_kernel<<<1536, 512, 0, stream>>>(XN, WQKVT, BQKV, nullptr, 0,
                                          QKV, 1536, 0, 512, 0, 12);
    hipMemsetAsync(O, 0, 33554432, stream);
    attn_kernel<<<1536, 256, 0, stream>>>(QKV, O);
    gemm_kernel<<<512, 512, 0, stream>>>(O, WOT, bo, x, 1024,
                                         out, 1024, 1, 512, 0, 4);
    ln_kernel<<<32768, 256, 0, stream>>>(out, 1024, ln2g, ln2b, H, 512);
    gemm_kernel<<<1024, 512, 0, stream>>>(H, W1T, b1, nullptr, 0,
                                          ACT, 1024, 0, 512, 1, 8);
    gemm_kernel<<<512, 512, 0, stream>>>(ACT, W2T, b2, x + 512, 1024,
                                         out + 512, 1024, 1, 1024, 0, 4);
}